// Round 1
// 805.433 us; speedup vs baseline: 1.0208x; 1.0208x over previous
//
#include <hip/hip_runtime.h>
#include <math.h>

#define NTOK 8192
#define NE   16
#define CAP  640
#define EC   (NE * CAP)                       // 10240

constexpr size_t DISP_SZ  = (size_t)NTOK * EC;   // 83,886,080 floats
constexpr size_t DISP4    = DISP_SZ / 4;         // 20,971,520 float4
constexpr size_t SCAL_OFF = 2 * DISP_SZ;         // 167,772,160
constexpr size_t LOG_OFF  = SCAL_OFF + 3;

// ws layout (bytes): key u64[8192] @0 ; pD double[2048*19] @65536 ; pI int[2048*16] @376832
#define WS_KEY 0
#define WS_PD  65536
#define WS_PI  376832

#define NRBLK 2048         // router blocks: 4 tokens each

typedef float vf4 __attribute__((ext_vector_type(4)));

// ---------------------------------------------------------------------------
// K_ROUTER: numerics FROZEN — bit-exact vs np-f32 ordering (passed R2/R3/R4
// in prior session). Zero path REMOVED: the output region is now written
// exactly once by k_write with the payload embedded.
// ---------------------------------------------------------------------------
__global__ __launch_bounds__(256) void k_router(
    const float4* __restrict__ X4, const float* __restrict__ Wg,
    const float* __restrict__ bg, float* __restrict__ out,
    unsigned long long* __restrict__ key,
    double* __restrict__ pD, int* __restrict__ pI)
{
    const int tid = threadIdx.x;

    __shared__ double sPex[4][NE];
    __shared__ float  sLog[4][NE];
    __shared__ double sLse[4];
    __shared__ int    sExp[4];

    const int w   = tid >> 6;                 // wave = token slot
    const int l   = tid & 63;
    const int n   = blockIdx.x * 4 + w;
    const int e   = l & 15;                   // this lane's expert (and spatial quad)
    const int g   = l >> 4;                   // channel group

    float wreg[16];                           // Wg[16g+i][e] in registers
#pragma unroll
    for (int i = 0; i < 16; i++)
        wreg[i] = Wg[(16 * g + i) * 16 + e];

    const float4* xb = X4 + (size_t)n * 1024;
    double dot = 0.0;
#pragma unroll
    for (int i = 0; i < 16; i++) {
        float4 v = xb[g * 256 + i * 16 + e];
        double s4 = ((double)v.x + (double)v.y) + ((double)v.z + (double)v.w);
        s4 += __shfl_xor(s4, 1, 64);          // spatial sum across the 16-lane group
        s4 += __shfl_xor(s4, 2, 64);
        s4 += __shfl_xor(s4, 4, 64);
        s4 += __shfl_xor(s4, 8, 64);
        float pooled = (float)(s4 * (1.0 / 64.0));   // np: f32 mean (exact /64)
        dot += (double)pooled * (double)wreg[i];
    }
    dot += __shfl_xor(dot, 16, 64);           // sum the 4 channel groups
    dot += __shfl_xor(dot, 32, 64);

    float raw = (float)dot + bg[e];           // f32 matmul result, + bg (f32 add)
    float lg  = raw / 1.5f;                   // IEEE f32 division
    lg = fminf(fmaxf(lg, -10.0f), 10.0f);

    // argmax over experts (first-index tie-break)
    float mv = lg; int mi = e;
#pragma unroll
    for (int off = 1; off <= 8; off <<= 1) {
        float ov = __shfl_xor(mv, off, 64);
        int   oi = __shfl_xor(mi, off, 64);
        if (ov > mv || (ov == mv && oi < mi)) { mv = ov; mi = oi; }
    }

    float d  = lg - mv;                       // f32 subtract
    float ex = (float)exp((double)d);         // correctly-rounded f32 exp
    double sd = (double)ex;
#pragma unroll
    for (int off = 1; off <= 8; off <<= 1)
        sd += __shfl_xor(sd, off, 64);        // sum of 16 exps
    float sumf = (float)sd;
    float ptop = 1.0f / sumf;
    double lse = (double)mv + log(sd);

    // pack sort key: [46:43]=expert  [42:13]=prob f32 bits  [12:0]=8191-n
    unsigned int pb = __float_as_uint(ptop);
    unsigned long long kk = ((unsigned long long)mi << 43)
                          | ((unsigned long long)pb << 13)
                          | (unsigned long long)(8191 - n);

    if (l == 0) { key[n] = kk; sLse[w] = lse; sExp[w] = mi; }
    if (l < 16) {
        out[LOG_OFF + (size_t)n * 16 + e] = lg;
        sPex[w][e] = (double)ex / sd;
        sLog[w][e] = lg;
    }
    __syncthreads();

    if (tid < 16) {
        pD[blockIdx.x * 19 + 3 + tid] =
            sPex[0][tid] + sPex[1][tid] + sPex[2][tid] + sPex[3][tid];
        pI[blockIdx.x * 16 + tid] = (sExp[0] == tid) + (sExp[1] == tid)
                                  + (sExp[2] == tid) + (sExp[3] == tid);
    } else if (tid == 16) {
        double z = 0.0;
        for (int i = 0; i < 4; i++) z += sLse[i] * sLse[i];
        pD[blockIdx.x * 19 + 0] = z;
    } else if (tid == 17) {
        double s = 0.0;
        for (int i = 0; i < 4; i++)
            for (int j = 0; j < 16; j++) s += (double)sLog[i][j];
        pD[blockIdx.x * 19 + 1] = s;
    } else if (tid == 18) {
        double s = 0.0;
        for (int i = 0; i < 4; i++)
            for (int j = 0; j < 16; j++) {
                double v = (double)sLog[i][j]; s += v * v;
            }
        pD[blockIdx.x * 19 + 2] = s;
    }
}

// ---------------------------------------------------------------------------
// K_WRITE: blockIdx < 1024 -> rank its 8 tokens (keys staged in LDS, scan
// unrolled x4) then stream the full dispatch+combine rows with the single
// 1.0 embedded in-register. Each output byte is written EXACTLY ONCE with
// plain coalesced float4 stores (the harness fill proves plain dwordx4
// stores hit 78% of HBM peak on this region; the old NT zero+scatter path
// did not). For surviving top-1 tokens combine weight = prob/prob = 1.0,
// so dispatch and combine rows are numerically identical.
// blockIdx == 1024 -> finalize reductions (unchanged).
// ---------------------------------------------------------------------------
__global__ __launch_bounds__(256) void k_write(
    const unsigned long long* __restrict__ key,
    const double* __restrict__ pD, const int* __restrict__ pI,
    float* __restrict__ out)
{
    __shared__ unsigned long long skey[NTOK];   // 64 KB (aliased by finalize)
    __shared__ int sFid[8];                     // per-token float index in row, or -1
    const int tid = threadIdx.x;

    if (blockIdx.x < 1024) {
        // stage all keys: 16B per lane, coalesced
        {
            const ulonglong2* kp = (const ulonglong2*)key;
            ulonglong2* sp = (ulonglong2*)skey;
#pragma unroll
            for (int k = 0; k < 16; k++)
                sp[tid + 256 * k] = kp[tid + 256 * k];
        }
        __syncthreads();

        // ---- rank: 32 lanes per token, 4 independent accumulators ----
        const int grp = tid >> 5;               // token slot 0..7
        const int sub = tid & 31;
        const int tok = blockIdx.x * 8 + grp;
        const unsigned long long me   = skey[tok];
        const unsigned long long my_e = me >> 43;

        int c0 = 0, c1 = 0, c2 = 0, c3 = 0;
        for (int m = sub; m < NTOK; m += 128) {
            unsigned long long k0 = skey[m];
            unsigned long long k1 = skey[m + 32];
            unsigned long long k2 = skey[m + 64];
            unsigned long long k3 = skey[m + 96];
            c0 += ((k0 >> 43) == my_e && k0 > me) ? 1 : 0;
            c1 += ((k1 >> 43) == my_e && k1 > me) ? 1 : 0;
            c2 += ((k2 >> 43) == my_e && k2 > me) ? 1 : 0;
            c3 += ((k3 >> 43) == my_e && k3 > me) ? 1 : 0;
        }
        int cnt = (c0 + c1) + (c2 + c3);
#pragma unroll
        for (int off = 16; off >= 1; off >>= 1)
            cnt += __shfl_down(cnt, off, 32);

        if (sub == 0)
            sFid[grp] = (cnt < CAP) ? (int)(my_e * CAP + (unsigned long long)cnt)
                                    : -1;
        __syncthreads();

        // ---- stream rows: 8 tokens x 2560 float4 x 2 regions ----
        vf4* o4 = (vf4*)out;
#pragma unroll
        for (int j = 0; j < 8; j++) {
            const size_t base = (size_t)(blockIdx.x * 8 + j) * (EC / 4);
            const int fid  = sFid[j];
            const int f4   = fid >> 2;          // -1 stays -1: never matches
            const int comp = fid & 3;
#pragma unroll
            for (int k = 0; k < 10; k++) {
                const int p = tid + 256 * k;
                vf4 z = {0.f, 0.f, 0.f, 0.f};
                if (p == f4) {                  // at most 1 lane per row
                    if      (comp == 0) z.x = 1.0f;
                    else if (comp == 1) z.y = 1.0f;
                    else if (comp == 2) z.z = 1.0f;
                    else                z.w = 1.0f;
                }
                o4[base + p]         = z;       // dispatch
                o4[DISP4 + base + p] = z;       // combine
            }
        }
        return;
    }

    // ---- finalize path (one block): reduce 2048 partial rows ----
    double* sD = (double*)skey;               // [256][20] = 40960 B
    int*    sI = (int*)(skey + 5120);         // [256][16] = 16384 B
    double a[19];
#pragma unroll
    for (int f = 0; f < 19; f++) a[f] = 0.0;
    int ci[NE];
#pragma unroll
    for (int f = 0; f < NE; f++) ci[f] = 0;

    for (int b = tid; b < 2048; b += 256) {
        const double* rowD = pD + b * 19;
#pragma unroll
        for (int f = 0; f < 19; f++) a[f] += rowD[f];
        const int* rowI = pI + b * NE;
#pragma unroll
        for (int f = 0; f < NE; f++) ci[f] += rowI[f];
    }
#pragma unroll
    for (int f = 0; f < 19; f++) sD[tid * 20 + f] = a[f];
#pragma unroll
    for (int f = 0; f < NE; f++) sI[tid * 16 + f] = ci[f];
    __syncthreads();

    if (tid == 0) {
        double tot[19];
        for (int f = 0; f < 19; f++) tot[f] = 0.0;
        int totI[NE];
        for (int f = 0; f < NE; f++) totI[f] = 0;
        for (int i = 0; i < 256; i++) {
            for (int f = 0; f < 19; f++) tot[f] += sD[i * 20 + f];
            for (int f = 0; f < NE; f++) totI[f] += sI[i * 16 + f];
        }
        double z = tot[0] / (double)NTOK;
        double aux = 0.0;
        for (int e = 0; e < NE; e++) {
            int kept = totI[e] < CAP ? totI[e] : CAP;
            aux += ((double)kept / (double)NTOK) * (tot[3 + e] / (double)NTOK);
        }
        aux *= (double)NE;
        double cntall = (double)NTOK * NE;
        double mean = tot[1] / cntall;
        double var  = tot[2] / cntall - mean * mean;
        if (var < 0.0) var = 0.0;
        out[SCAL_OFF + 0] = (float)z;
        out[SCAL_OFF + 1] = (float)aux;
        out[SCAL_OFF + 2] = (float)sqrt(var);
    }
}

extern "C" void kernel_launch(void* const* d_in, const int* in_sizes, int n_in,
                              void* d_out, int out_size, void* d_ws, size_t ws_size,
                              hipStream_t stream)
{
    const float* X  = (const float*)d_in[0];
    const float* Wg = (const float*)d_in[1];
    const float* bg = (const float*)d_in[2];
    float* out = (float*)d_out;

    char* ws = (char*)d_ws;
    unsigned long long* key = (unsigned long long*)(ws + WS_KEY);
    double* pD = (double*)(ws + WS_PD);
    int*    pI = (int*)   (ws + WS_PI);

    k_router<<<NRBLK, 256, 0, stream>>>((const float4*)X, Wg, bg, out,
                                        key, pD, pI);
    k_write<<<1025, 256, 0, stream>>>(key, pD, pI, out);
}

// Round 2
// 787.610 us; speedup vs baseline: 1.0439x; 1.0226x over previous
//
#include <hip/hip_runtime.h>
#include <math.h>

#define NTOK 8192
#define NE   16
#define CAP  640
#define EC   (NE * CAP)                       // 10240

constexpr size_t DISP_SZ  = (size_t)NTOK * EC;   // 83,886,080 floats
constexpr size_t SCAL_OFF = 2 * DISP_SZ;         // 167,772,160
constexpr size_t LOG_OFF  = SCAL_OFF + 3;

// ws layout (bytes): key u64[8192] @0 ; pD double[2048*19] @65536 ; pI int[2048*16] @376832
#define WS_KEY 0
#define WS_PD  65536
#define WS_PI  376832

#define NZBLK 5120         // zero blocks: each writes 8192 float4 = 128 KB
#define NRBLK 2048         // router blocks: 4 tokens each

typedef float vf4 __attribute__((ext_vector_type(4)));

// ---------------------------------------------------------------------------
// K_MAIN: blockIdx < NRBLK -> router (numerics FROZEN — bit-exact vs np-f32
// ordering); blockIdx >= NRBLK -> zero a 128 KB chunk of dispatch+combine
// with PLAIN coalesced float4 stores (harness fill proves plain dwordx4 hits
// 78% of HBM peak on this exact region; Round-0 NT stores bought nothing).
// Fusing router+zero overlaps the 134 MB X read with the 671 MB zero stream
// in one BW window instead of serializing them across a kernel boundary.
// ---------------------------------------------------------------------------
__global__ __launch_bounds__(256) void k_main(
    const float4* __restrict__ X4, const float* __restrict__ Wg,
    const float* __restrict__ bg, float* __restrict__ out,
    unsigned long long* __restrict__ key,
    double* __restrict__ pD, int* __restrict__ pI)
{
    const int tid = threadIdx.x;

    if (blockIdx.x >= NRBLK) {
        // ---- zero path: 8192 float4 per block, coalesced, plain stores ----
        vf4* o4 = (vf4*)out + (size_t)(blockIdx.x - NRBLK) * 8192;
        const vf4 z = {0.f, 0.f, 0.f, 0.f};
#pragma unroll
        for (int k = 0; k < 32; k++)
            o4[tid + 256 * k] = z;
        return;
    }

    // ---- router path (frozen) ----
    __shared__ double sPex[4][NE];
    __shared__ float  sLog[4][NE];
    __shared__ double sLse[4];
    __shared__ int    sExp[4];

    const int w   = tid >> 6;                 // wave = token slot
    const int l   = tid & 63;
    const int n   = blockIdx.x * 4 + w;
    const int e   = l & 15;                   // this lane's expert (and spatial quad)
    const int g   = l >> 4;                   // channel group

    float wreg[16];                           // Wg[16g+i][e] in registers
#pragma unroll
    for (int i = 0; i < 16; i++)
        wreg[i] = Wg[(16 * g + i) * 16 + e];

    const float4* xb = X4 + (size_t)n * 1024;
    double dot = 0.0;
#pragma unroll
    for (int i = 0; i < 16; i++) {
        float4 v = xb[g * 256 + i * 16 + e];
        double s4 = ((double)v.x + (double)v.y) + ((double)v.z + (double)v.w);
        s4 += __shfl_xor(s4, 1, 64);          // spatial sum across the 16-lane group
        s4 += __shfl_xor(s4, 2, 64);
        s4 += __shfl_xor(s4, 4, 64);
        s4 += __shfl_xor(s4, 8, 64);
        float pooled = (float)(s4 * (1.0 / 64.0));   // np: f32 mean (exact /64)
        dot += (double)pooled * (double)wreg[i];
    }
    dot += __shfl_xor(dot, 16, 64);           // sum the 4 channel groups
    dot += __shfl_xor(dot, 32, 64);

    float raw = (float)dot + bg[e];           // f32 matmul result, + bg (f32 add)
    float lg  = raw / 1.5f;                   // IEEE f32 division
    lg = fminf(fmaxf(lg, -10.0f), 10.0f);

    // argmax over experts (first-index tie-break)
    float mv = lg; int mi = e;
#pragma unroll
    for (int off = 1; off <= 8; off <<= 1) {
        float ov = __shfl_xor(mv, off, 64);
        int   oi = __shfl_xor(mi, off, 64);
        if (ov > mv || (ov == mv && oi < mi)) { mv = ov; mi = oi; }
    }

    float d  = lg - mv;                       // f32 subtract
    float ex = (float)exp((double)d);         // correctly-rounded f32 exp
    double sd = (double)ex;
#pragma unroll
    for (int off = 1; off <= 8; off <<= 1)
        sd += __shfl_xor(sd, off, 64);        // sum of 16 exps
    float sumf = (float)sd;
    float ptop = 1.0f / sumf;
    double lse = (double)mv + log(sd);

    // pack sort key: [46:43]=expert  [42:13]=prob f32 bits  [12:0]=8191-n
    unsigned int pb = __float_as_uint(ptop);
    unsigned long long kk = ((unsigned long long)mi << 43)
                          | ((unsigned long long)pb << 13)
                          | (unsigned long long)(8191 - n);

    if (l == 0) { key[n] = kk; sLse[w] = lse; sExp[w] = mi; }
    if (l < 16) {
        out[LOG_OFF + (size_t)n * 16 + e] = lg;
        sPex[w][e] = (double)ex / sd;
        sLog[w][e] = lg;
    }
    __syncthreads();

    if (tid < 16) {
        pD[blockIdx.x * 19 + 3 + tid] =
            sPex[0][tid] + sPex[1][tid] + sPex[2][tid] + sPex[3][tid];
        pI[blockIdx.x * 16 + tid] = (sExp[0] == tid) + (sExp[1] == tid)
                                  + (sExp[2] == tid) + (sExp[3] == tid);
    } else if (tid == 16) {
        double z = 0.0;
        for (int i = 0; i < 4; i++) z += sLse[i] * sLse[i];
        pD[blockIdx.x * 19 + 0] = z;
    } else if (tid == 17) {
        double s = 0.0;
        for (int i = 0; i < 4; i++)
            for (int j = 0; j < 16; j++) s += (double)sLog[i][j];
        pD[blockIdx.x * 19 + 1] = s;
    } else if (tid == 18) {
        double s = 0.0;
        for (int i = 0; i < 4; i++)
            for (int j = 0; j < 16; j++) {
                double v = (double)sLog[i][j]; s += v * v;
            }
        pD[blockIdx.x * 19 + 2] = s;
    }
}

// ---------------------------------------------------------------------------
// K_SCATTER: blocks 0..1023 -> rank 8 tokens each (keys scanned straight
// from global: the 64 KB key array is L2-resident across all blocks; no LDS
// staging -> no 64 KB/block occupancy cap, no barrier) and write the two
// 1.0 floats per surviving token over the zeroed region.
// block 1024 -> finalize reductions via shuffle (LDS footprint ~1 KB).
// ---------------------------------------------------------------------------
__global__ __launch_bounds__(256) void k_scatter(
    const unsigned long long* __restrict__ key,
    const double* __restrict__ pD, const int* __restrict__ pI,
    float* __restrict__ out)
{
    __shared__ double sW[4][19];
    __shared__ int    sWi[4][16];
    const int tid = threadIdx.x;

    if (blockIdx.x < 1024) {
        const int grp = tid >> 5;               // token slot 0..7
        const int sub = tid & 31;
        const int tok = blockIdx.x * 8 + grp;
        const unsigned long long me   = key[tok];
        const unsigned long long my_e = me >> 43;

        int c0 = 0, c1 = 0, c2 = 0, c3 = 0;
        for (int m = sub; m < NTOK; m += 128) {
            unsigned long long k0 = key[m];
            unsigned long long k1 = key[m + 32];
            unsigned long long k2 = key[m + 64];
            unsigned long long k3 = key[m + 96];
            c0 += ((k0 >> 43) == my_e && k0 > me) ? 1 : 0;
            c1 += ((k1 >> 43) == my_e && k1 > me) ? 1 : 0;
            c2 += ((k2 >> 43) == my_e && k2 > me) ? 1 : 0;
            c3 += ((k3 >> 43) == my_e && k3 > me) ? 1 : 0;
        }
        int cnt = (c0 + c1) + (c2 + c3);
#pragma unroll
        for (int off = 16; off >= 1; off >>= 1)
            cnt += __shfl_down(cnt, off, 32);

        if (sub == 0 && cnt < CAP) {
            size_t idx = (size_t)tok * EC + (size_t)my_e * CAP + (size_t)cnt;
            out[idx]           = 1.0f;          // dispatch
            out[DISP_SZ + idx] = 1.0f;          // combine (= prob/prob = 1.0)
        }
        return;
    }

    // ---- finalize path (one block): reduce 2048 partial rows ----
    double a[19];
#pragma unroll
    for (int f = 0; f < 19; f++) a[f] = 0.0;
    int ci[NE];
#pragma unroll
    for (int f = 0; f < NE; f++) ci[f] = 0;

    for (int b = tid; b < 2048; b += 256) {
        const double* rowD = pD + b * 19;
#pragma unroll
        for (int f = 0; f < 19; f++) a[f] += rowD[f];
        const int* rowI = pI + b * NE;
#pragma unroll
        for (int f = 0; f < NE; f++) ci[f] += rowI[f];
    }
    // wave-level reduction (64 lanes -> lane 0)
#pragma unroll
    for (int off = 32; off >= 1; off >>= 1) {
#pragma unroll
        for (int f = 0; f < 19; f++) a[f] += __shfl_down(a[f], off, 64);
#pragma unroll
        for (int f = 0; f < NE; f++) ci[f] += __shfl_down(ci[f], off, 64);
    }
    if ((tid & 63) == 0) {
        const int wv = tid >> 6;
#pragma unroll
        for (int f = 0; f < 19; f++) sW[wv][f] = a[f];
#pragma unroll
        for (int f = 0; f < NE; f++) sWi[wv][f] = ci[f];
    }
    __syncthreads();

    if (tid == 0) {
        double tot[19];
        for (int f = 0; f < 19; f++)
            tot[f] = sW[0][f] + sW[1][f] + sW[2][f] + sW[3][f];
        int totI[NE];
        for (int f = 0; f < NE; f++)
            totI[f] = sWi[0][f] + sWi[1][f] + sWi[2][f] + sWi[3][f];

        double z = tot[0] / (double)NTOK;
        double aux = 0.0;
        for (int e = 0; e < NE; e++) {
            int kept = totI[e] < CAP ? totI[e] : CAP;
            aux += ((double)kept / (double)NTOK) * (tot[3 + e] / (double)NTOK);
        }
        aux *= (double)NE;
        double cntall = (double)NTOK * NE;
        double mean = tot[1] / cntall;
        double var  = tot[2] / cntall - mean * mean;
        if (var < 0.0) var = 0.0;
        out[SCAL_OFF + 0] = (float)z;
        out[SCAL_OFF + 1] = (float)aux;
        out[SCAL_OFF + 2] = (float)sqrt(var);
    }
}

extern "C" void kernel_launch(void* const* d_in, const int* in_sizes, int n_in,
                              void* d_out, int out_size, void* d_ws, size_t ws_size,
                              hipStream_t stream)
{
    const float* X  = (const float*)d_in[0];
    const float* Wg = (const float*)d_in[1];
    const float* bg = (const float*)d_in[2];
    float* out = (float*)d_out;

    char* ws = (char*)d_ws;
    unsigned long long* key = (unsigned long long*)(ws + WS_KEY);
    double* pD = (double*)(ws + WS_PD);
    int*    pI = (int*)   (ws + WS_PI);

    k_main<<<NRBLK + NZBLK, 256, 0, stream>>>((const float4*)X, Wg, bg, out,
                                              key, pD, pI);
    k_scatter<<<1025, 256, 0, stream>>>(key, pD, pI, out);
}

// Round 3
// 764.986 us; speedup vs baseline: 1.0748x; 1.0296x over previous
//
#include <hip/hip_runtime.h>
#include <math.h>

#define NTOK 8192
#define NE   16
#define CAP  640
#define EC   (NE * CAP)                       // 10240

constexpr size_t DISP_SZ  = (size_t)NTOK * EC;   // 83,886,080 floats
constexpr size_t SCAL_OFF = 2 * DISP_SZ;         // 167,772,160
constexpr size_t LOG_OFF  = SCAL_OFF + 3;

// ws layout (bytes): key u64[8192] @0 ; pD double[2048*19] @65536 ; pI int[2048*16] @376832
#define WS_KEY 0
#define WS_PD  65536
#define WS_PI  376832

#define NZBLK 5120         // zero blocks: each writes 8192 float4 = 128 KB
#define NRBLK 2048         // router blocks: 4 tokens each
#define NSBLK 256          // scatter blocks: 32 tokens each

typedef float vf4 __attribute__((ext_vector_type(4)));

// ---------------------------------------------------------------------------
// K_MAIN: blockIdx < NRBLK -> router (numerics FROZEN — bit-exact vs np-f32
// ordering); blockIdx >= NRBLK -> zero a 128 KB chunk of dispatch+combine
// with plain coalesced float4 stores. Fusing router+zero overlaps the 134 MB
// X read with the 671 MB zero stream in one BW window. At-floor per R2.
// ---------------------------------------------------------------------------
__global__ __launch_bounds__(256) void k_main(
    const float4* __restrict__ X4, const float* __restrict__ Wg,
    const float* __restrict__ bg, float* __restrict__ out,
    unsigned long long* __restrict__ key,
    double* __restrict__ pD, int* __restrict__ pI)
{
    const int tid = threadIdx.x;

    if (blockIdx.x >= NRBLK) {
        // ---- zero path: 8192 float4 per block, coalesced, plain stores ----
        vf4* o4 = (vf4*)out + (size_t)(blockIdx.x - NRBLK) * 8192;
        const vf4 z = {0.f, 0.f, 0.f, 0.f};
#pragma unroll
        for (int k = 0; k < 32; k++)
            o4[tid + 256 * k] = z;
        return;
    }

    // ---- router path (frozen) ----
    __shared__ double sPex[4][NE];
    __shared__ float  sLog[4][NE];
    __shared__ double sLse[4];
    __shared__ int    sExp[4];

    const int w   = tid >> 6;                 // wave = token slot
    const int l   = tid & 63;
    const int n   = blockIdx.x * 4 + w;
    const int e   = l & 15;                   // this lane's expert (and spatial quad)
    const int g   = l >> 4;                   // channel group

    float wreg[16];                           // Wg[16g+i][e] in registers
#pragma unroll
    for (int i = 0; i < 16; i++)
        wreg[i] = Wg[(16 * g + i) * 16 + e];

    const float4* xb = X4 + (size_t)n * 1024;
    double dot = 0.0;
#pragma unroll
    for (int i = 0; i < 16; i++) {
        float4 v = xb[g * 256 + i * 16 + e];
        double s4 = ((double)v.x + (double)v.y) + ((double)v.z + (double)v.w);
        s4 += __shfl_xor(s4, 1, 64);          // spatial sum across the 16-lane group
        s4 += __shfl_xor(s4, 2, 64);
        s4 += __shfl_xor(s4, 4, 64);
        s4 += __shfl_xor(s4, 8, 64);
        float pooled = (float)(s4 * (1.0 / 64.0));   // np: f32 mean (exact /64)
        dot += (double)pooled * (double)wreg[i];
    }
    dot += __shfl_xor(dot, 16, 64);           // sum the 4 channel groups
    dot += __shfl_xor(dot, 32, 64);

    float raw = (float)dot + bg[e];           // f32 matmul result, + bg (f32 add)
    float lg  = raw / 1.5f;                   // IEEE f32 division
    lg = fminf(fmaxf(lg, -10.0f), 10.0f);

    // argmax over experts (first-index tie-break)
    float mv = lg; int mi = e;
#pragma unroll
    for (int off = 1; off <= 8; off <<= 1) {
        float ov = __shfl_xor(mv, off, 64);
        int   oi = __shfl_xor(mi, off, 64);
        if (ov > mv || (ov == mv && oi < mi)) { mv = ov; mi = oi; }
    }

    float d  = lg - mv;                       // f32 subtract
    float ex = (float)exp((double)d);         // correctly-rounded f32 exp
    double sd = (double)ex;
#pragma unroll
    for (int off = 1; off <= 8; off <<= 1)
        sd += __shfl_xor(sd, off, 64);        // sum of 16 exps
    float sumf = (float)sd;
    float ptop = 1.0f / sumf;
    double lse = (double)mv + log(sd);

    // pack sort key: [46:43]=expert  [42:13]=prob f32 bits  [12:0]=8191-n
    unsigned int pb = __float_as_uint(ptop);
    unsigned long long kk = ((unsigned long long)mi << 43)
                          | ((unsigned long long)pb << 13)
                          | (unsigned long long)(8191 - n);

    if (l == 0) { key[n] = kk; sLse[w] = lse; sExp[w] = mi; }
    if (l < 16) {
        out[LOG_OFF + (size_t)n * 16 + e] = lg;
        sPex[w][e] = (double)ex / sd;
        sLog[w][e] = lg;
    }
    __syncthreads();

    if (tid < 16) {
        pD[blockIdx.x * 19 + 3 + tid] =
            sPex[0][tid] + sPex[1][tid] + sPex[2][tid] + sPex[3][tid];
        pI[blockIdx.x * 16 + tid] = (sExp[0] == tid) + (sExp[1] == tid)
                                  + (sExp[2] == tid) + (sExp[3] == tid);
    } else if (tid == 16) {
        double z = 0.0;
        for (int i = 0; i < 4; i++) z += sLse[i] * sLse[i];
        pD[blockIdx.x * 19 + 0] = z;
    } else if (tid == 17) {
        double s = 0.0;
        for (int i = 0; i < 4; i++)
            for (int j = 0; j < 16; j++) s += (double)sLog[i][j];
        pD[blockIdx.x * 19 + 1] = s;
    } else if (tid == 18) {
        double s = 0.0;
        for (int i = 0; i < 4; i++)
            for (int j = 0; j < 16; j++) {
                double v = (double)sLog[i][j]; s += v * v;
            }
        pD[blockIdx.x * 19 + 2] = s;
    }
}

// ---------------------------------------------------------------------------
// K_SCATTER: blocks 0..255 -> 32 tokens each, keys staged ONCE in LDS
// (64 KB; 256 blocks -> 1 block/CU, so no occupancy tax). 8 lanes/token;
// the scan's per-wave LDS pattern is an 8-way same-address broadcast
// (free per m136), 64B unique per instr, conflict-free. Aggregate L2 read
// drops 512 MB -> 16 MB vs R2. Scan predicate FROZEN (identical semantics).
// block 256 -> finalize reductions via shuffle.
// ---------------------------------------------------------------------------
__global__ __launch_bounds__(256) void k_scatter(
    const unsigned long long* __restrict__ key,
    const double* __restrict__ pD, const int* __restrict__ pI,
    float* __restrict__ out)
{
    __shared__ unsigned long long skey[NTOK];   // 64 KB
    __shared__ double sW[4][19];
    __shared__ int    sWi[4][16];
    const int tid = threadIdx.x;

    if (blockIdx.x < NSBLK) {
        // stage all keys: 16B per lane, coalesced
        {
            const ulonglong2* kp = (const ulonglong2*)key;
            ulonglong2* sp = (ulonglong2*)skey;
#pragma unroll
            for (int k = 0; k < 16; k++)
                sp[tid + 256 * k] = kp[tid + 256 * k];
        }
        __syncthreads();

        const int grp = tid >> 3;               // token slot 0..31
        const int sub = tid & 7;
        const int tok = blockIdx.x * 32 + grp;
        const unsigned long long me   = skey[tok];
        const unsigned long long my_e = me >> 43;

        int cnt = 0;
#pragma unroll 8
        for (int m = sub; m < NTOK; m += 8) {
            unsigned long long km = skey[m];
            cnt += ((km >> 43) == my_e && km > me) ? 1 : 0;
        }
        cnt += __shfl_down(cnt, 4, 8);
        cnt += __shfl_down(cnt, 2, 8);
        cnt += __shfl_down(cnt, 1, 8);

        if (sub == 0 && cnt < CAP) {
            size_t idx = (size_t)tok * EC + (size_t)my_e * CAP + (size_t)cnt;
            out[idx]           = 1.0f;          // dispatch
            out[DISP_SZ + idx] = 1.0f;          // combine (= prob/prob = 1.0)
        }
        return;
    }

    // ---- finalize path (one block): reduce 2048 partial rows ----
    double a[19];
#pragma unroll
    for (int f = 0; f < 19; f++) a[f] = 0.0;
    int ci[NE];
#pragma unroll
    for (int f = 0; f < NE; f++) ci[f] = 0;

    for (int b = tid; b < 2048; b += 256) {
        const double* rowD = pD + b * 19;
#pragma unroll
        for (int f = 0; f < 19; f++) a[f] += rowD[f];
        const int* rowI = pI + b * NE;
#pragma unroll
        for (int f = 0; f < NE; f++) ci[f] += rowI[f];
    }
    // wave-level reduction (64 lanes -> lane 0)
#pragma unroll
    for (int off = 32; off >= 1; off >>= 1) {
#pragma unroll
        for (int f = 0; f < 19; f++) a[f] += __shfl_down(a[f], off, 64);
#pragma unroll
        for (int f = 0; f < NE; f++) ci[f] += __shfl_down(ci[f], off, 64);
    }
    if ((tid & 63) == 0) {
        const int wv = tid >> 6;
#pragma unroll
        for (int f = 0; f < 19; f++) sW[wv][f] = a[f];
#pragma unroll
        for (int f = 0; f < NE; f++) sWi[wv][f] = ci[f];
    }
    __syncthreads();

    if (tid == 0) {
        double tot[19];
        for (int f = 0; f < 19; f++)
            tot[f] = sW[0][f] + sW[1][f] + sW[2][f] + sW[3][f];
        int totI[NE];
        for (int f = 0; f < NE; f++)
            totI[f] = sWi[0][f] + sWi[1][f] + sWi[2][f] + sWi[3][f];

        double z = tot[0] / (double)NTOK;
        double aux = 0.0;
        for (int e = 0; e < NE; e++) {
            int kept = totI[e] < CAP ? totI[e] : CAP;
            aux += ((double)kept / (double)NTOK) * (tot[3 + e] / (double)NTOK);
        }
        aux *= (double)NE;
        double cntall = (double)NTOK * NE;
        double mean = tot[1] / cntall;
        double var  = tot[2] / cntall - mean * mean;
        if (var < 0.0) var = 0.0;
        out[SCAL_OFF + 0] = (float)z;
        out[SCAL_OFF + 1] = (float)aux;
        out[SCAL_OFF + 2] = (float)sqrt(var);
    }
}

extern "C" void kernel_launch(void* const* d_in, const int* in_sizes, int n_in,
                              void* d_out, int out_size, void* d_ws, size_t ws_size,
                              hipStream_t stream)
{
    const float* X  = (const float*)d_in[0];
    const float* Wg = (const float*)d_in[1];
    const float* bg = (const float*)d_in[2];
    float* out = (float*)d_out;

    char* ws = (char*)d_ws;
    unsigned long long* key = (unsigned long long*)(ws + WS_KEY);
    double* pD = (double*)(ws + WS_PD);
    int*    pI = (int*)   (ws + WS_PI);

    k_main<<<NRBLK + NZBLK, 256, 0, stream>>>((const float4*)X, Wg, bg, out,
                                              key, pD, pI);
    k_scatter<<<NSBLK + 1, 256, 0, stream>>>(key, pD, pI, out);
}